// Round 1
// baseline (12438.825 us; speedup 1.0000x reference)
//
#include <hip/hip_runtime.h>

// MultiTaskLSTM: B=512, T=1024, I=64, H=256
// Strategy: partition batch across 32 blocks (16 rows each); each block runs
// the full T=1024 recurrence locally (no grid sync). Per step, gates(16x1024)
// = [h|x_t](16x320) @ W^T via bf16 MFMA 16x16x32, W streamed from L2 in
// pre-packed fragment order. Elementwise gate math + c/h update in LDS.

typedef __attribute__((ext_vector_type(4))) float f32x4;
typedef __attribute__((ext_vector_type(8))) short bf16x8;
typedef __attribute__((ext_vector_type(8))) unsigned short u16x8;

#define B_SZ 512
#define T_SZ 1024
#define I_SZ 64
#define H_SZ 256
#define G4   1024          // 4*H
#define KTOT 320           // H + I
#define KFRAGS 10          // 320/32
#define NTILES 64          // 1024/16
#define MROWS 16
#define NBLK 32            // B_SZ / MROWS
#define NTHREADS 512
#define NWAVES 8
#define NT_PW 8            // n-tiles per wave (8*16 = 128 cols)
#define AST 328            // A_lds row stride (bf16 elems): 320 + 8 pad
#define GST 1032           // gates_lds row stride (f32): 1024 + 8 pad

#define WT_ELEMS (NTILES * KFRAGS * 64)   // 40960 fragments of 8 bf16 (16B)

__device__ __forceinline__ unsigned short f2bf(float f) {
    unsigned int u = __builtin_bit_cast(unsigned int, f);
    unsigned int r = (u + 0x7FFFu + ((u >> 16) & 1u)) >> 16;
    return (unsigned short)r;
}
__device__ __forceinline__ float bf2f(unsigned short s) {
    unsigned int u = ((unsigned int)s) << 16;
    return __builtin_bit_cast(float, u);
}
__device__ __forceinline__ float sigm(float x) {
    return 1.0f / (1.0f + exp2f(-1.44269504f * x));
}
__device__ __forceinline__ float tanhfast(float x) {
    float e = exp2f(2.88539008f * x);   // e^(2x)
    return 1.0f - 2.0f / (e + 1.0f);
}

// Pack W = [W_hh | W_ih] (1024 x 320) into MFMA B-fragment stream order:
// frag index = (nt*KFRAGS + kf)*64 + lane ; 8 bf16 each:
//   n = nt*16 + (lane&15), k = kf*32 + (lane>>4)*8 + j
// Also bias_sum = b_ih + b_hh.
__global__ void prep_kernel(const float* __restrict__ W_ih,
                            const float* __restrict__ W_hh,
                            const float* __restrict__ b_ih,
                            const float* __restrict__ b_hh,
                            unsigned short* __restrict__ Wt,
                            float* __restrict__ bias) {
    int gid = blockIdx.x * blockDim.x + threadIdx.x;
    if (gid < WT_ELEMS) {
        int lane = gid & 63;
        int rest = gid >> 6;
        int kf = rest % KFRAGS;
        int nt = rest / KFRAGS;
        int n  = nt * 16 + (lane & 15);
        int k0 = kf * 32 + (lane >> 4) * 8;
        u16x8 v;
        #pragma unroll
        for (int j = 0; j < 8; ++j) {
            int k = k0 + j;
            float w = (k < H_SZ) ? W_hh[n * H_SZ + k]
                                 : W_ih[n * I_SZ + (k - H_SZ)];
            v[j] = f2bf(w);
        }
        ((u16x8*)Wt)[gid] = v;
    } else {
        int j = gid - WT_ELEMS;
        if (j < G4) bias[j] = b_ih[j] + b_hh[j];
    }
}

__global__ __launch_bounds__(NTHREADS)
void lstm_kernel(const float* __restrict__ x,
                 const unsigned short* __restrict__ Wt,
                 const float* __restrict__ bias,
                 const float* __restrict__ W_dir, const float* __restrict__ b_dir,
                 const float* __restrict__ W_q,   const float* __restrict__ b_q,
                 const float* __restrict__ W_rr,  const float* __restrict__ b_rr,
                 const float* __restrict__ W_sl,  const float* __restrict__ b_sl,
                 float* __restrict__ out) {
    __shared__ unsigned short A_lds[MROWS * AST];   // [h(256) | x_t(64)] bf16
    __shared__ float gates_lds[MROWS * GST];
    __shared__ float c_lds[MROWS * H_SZ];
    __shared__ float bias_lds[G4];

    const int tid  = threadIdx.x;
    const int lane = tid & 63;
    const int wave = tid >> 6;
    const int b0   = blockIdx.x * MROWS;

    // init: h = 0, c = 0, bias to LDS, load x_0
    for (int i = tid; i < MROWS * AST; i += NTHREADS) A_lds[i] = 0;
    for (int i = tid; i < MROWS * H_SZ; i += NTHREADS) c_lds[i] = 0.0f;
    for (int i = tid; i < G4; i += NTHREADS) bias_lds[i] = bias[i];
    for (int i = tid; i < MROWS * I_SZ; i += NTHREADS) {
        int r = i >> 6, cc = i & 63;
        A_lds[r * AST + H_SZ + cc] =
            f2bf(x[(size_t)(b0 + r) * (T_SZ * I_SZ) + cc]);
    }
    __syncthreads();

    // A-fragment LDS byte address: row = lane&15, k-group = lane>>4
    const int abyte = (lane & 15) * (AST * 2) + (lane >> 4) * 16;

    for (int t = 0; t < T_SZ; ++t) {
        // ---- load A fragments (h|x_t) from LDS ----
        bf16x8 af[KFRAGS];
        #pragma unroll
        for (int kf = 0; kf < KFRAGS; ++kf)
            af[kf] = *(const bf16x8*)((const char*)A_lds + abyte + kf * 64);

        // ---- GEMM: stream W fragments from L2, MFMA accumulate ----
        #pragma unroll
        for (int nt = 0; nt < NT_PW; ++nt) {
            int gt = wave * NT_PW + nt;
            const bf16x8* bp = (const bf16x8*)Wt + (size_t)gt * (KFRAGS * 64) + lane;
            f32x4 acc = {0.0f, 0.0f, 0.0f, 0.0f};
            #pragma unroll
            for (int kf = 0; kf < KFRAGS; ++kf) {
                bf16x8 bfr = bp[kf * 64];
                acc = __builtin_amdgcn_mfma_f32_16x16x32_bf16(af[kf], bfr, acc, 0, 0, 0);
            }
            int col   = gt * 16 + (lane & 15);
            int rbase = (lane >> 4) * 4;
            #pragma unroll
            for (int r = 0; r < 4; ++r)
                gates_lds[(rbase + r) * GST + col] = acc[r];
        }
        __syncthreads();

        // ---- prefetch x_{t+1} into regs (hide under elementwise) ----
        float xv[2] = {0.0f, 0.0f};
        if (t + 1 < T_SZ) {
            #pragma unroll
            for (int it = 0; it < 2; ++it) {
                int i = it * NTHREADS + tid;   // 0..1023
                int r = i >> 6, cc = i & 63;
                xv[it] = x[(size_t)(b0 + r) * (T_SZ * I_SZ)
                           + (size_t)(t + 1) * I_SZ + cc];
            }
        }

        // ---- elementwise: gates -> (c,h), 16*256 items, 8 per thread ----
        #pragma unroll
        for (int it = 0; it < 8; ++it) {
            int idx = it * NTHREADS + tid;
            int r = idx >> 8, j = idx & 255;
            float gi = gates_lds[r * GST + j]       + bias_lds[j];
            float gf = gates_lds[r * GST + 256 + j] + bias_lds[256 + j];
            float gg = gates_lds[r * GST + 512 + j] + bias_lds[512 + j];
            float go = gates_lds[r * GST + 768 + j] + bias_lds[768 + j];
            float ii = sigm(gi);
            float ff = sigm(gf);
            float gG = tanhfast(gg);
            float oo = sigm(go);
            float c  = ff * c_lds[r * H_SZ + j] + ii * gG;
            c_lds[r * H_SZ + j] = c;
            float h  = oo * tanhfast(c);
            A_lds[r * AST + j] = f2bf(h);
        }

        // ---- store x_{t+1} into A_lds ----
        if (t + 1 < T_SZ) {
            #pragma unroll
            for (int it = 0; it < 2; ++it) {
                int i = it * NTHREADS + tid;
                int r = i >> 6, cc = i & 63;
                A_lds[r * AST + H_SZ + cc] = f2bf(xv[it]);
            }
        }
        __syncthreads();
    }

    // ---- heads: 16 rows x 8 outputs ----
    if (tid < MROWS * 8) {
        int r = tid >> 3, c = tid & 7;
        const float* wrow;
        float bb;
        if (c == 0)      { wrow = W_dir;                bb = b_dir[0]; }
        else if (c <= 5) { wrow = W_q + (c - 1) * H_SZ; bb = b_q[c - 1]; }
        else if (c == 6) { wrow = W_rr;                 bb = b_rr[0]; }
        else             { wrow = W_sl;                 bb = b_sl[0]; }
        float s = bb;
        for (int k = 0; k < H_SZ; ++k)
            s += bf2f(A_lds[r * AST + k]) * wrow[k];
        float v = (c == 0) ? tanhfast(s) : (c == 7) ? sigm(s) : s;
        out[(b0 + r) * 8 + c] = v;
    }
}

extern "C" void kernel_launch(void* const* d_in, const int* in_sizes, int n_in,
                              void* d_out, int out_size, void* d_ws, size_t ws_size,
                              hipStream_t stream) {
    const float* x     = (const float*)d_in[0];
    const float* W_ih  = (const float*)d_in[1];
    const float* W_hh  = (const float*)d_in[2];
    const float* b_ih  = (const float*)d_in[3];
    const float* b_hh  = (const float*)d_in[4];
    const float* W_dir = (const float*)d_in[5];
    const float* b_dir = (const float*)d_in[6];
    const float* W_q   = (const float*)d_in[7];
    const float* b_q   = (const float*)d_in[8];
    const float* W_rr  = (const float*)d_in[9];
    const float* b_rr  = (const float*)d_in[10];
    const float* W_sl  = (const float*)d_in[11];
    const float* b_sl  = (const float*)d_in[12];

    unsigned short* Wt = (unsigned short*)d_ws;
    float* bias = (float*)((char*)d_ws + (size_t)WT_ELEMS * 16);

    // 40960 fragment lanes + 1024 bias = 41984 = 164 * 256
    prep_kernel<<<164, 256, 0, stream>>>(W_ih, W_hh, b_ih, b_hh, Wt, bias);
    lstm_kernel<<<NBLK, NTHREADS, 0, stream>>>(x, Wt, bias,
                                               W_dir, b_dir, W_q, b_q,
                                               W_rr, b_rr, W_sl, b_sl,
                                               (float*)d_out);
}